// Round 1
// baseline (2196.158 us; speedup 1.0000x reference)
//
#include <hip/hip_runtime.h>

#define F_IN 128
#define HID 128
#define HID4 32

static inline size_t alignup(size_t x) { return (x + 255) & ~(size_t)255; }

// ---------------- degree / normalization ----------------

__global__ void deg_init_k(int* __restrict__ deg, int n) {
    int i = blockIdx.x * blockDim.x + threadIdx.x;
    if (i < n) deg[i] = 1;  // self-loop contributes 1
}

__global__ void deg_count_k(const int* __restrict__ dst, int* __restrict__ deg, int ne) {
    int e = blockIdx.x * blockDim.x + threadIdx.x;
    if (e < ne) atomicAdd(&deg[dst[e]], 1);
}

__global__ void dis_k(const int* __restrict__ deg, float* __restrict__ dis, int n) {
    int i = blockIdx.x * blockDim.x + threadIdx.x;
    if (i < n) dis[i] = rsqrtf((float)deg[i]);  // deg >= 1 always
}

// ---------------- GEMMs (fp32 vector ALU; no fp32 MFMA on CDNA4) ----------------

// out[row][0:128] = (relu?)in[row][0:128] @ W[128][128]
// block = 256 threads: 8 rows x 32 col-quads
template<bool RELUIN>
__global__ void gemm_k128_n128(const float* __restrict__ in, const float* __restrict__ W,
                               float* __restrict__ out, int n_rows) {
    __shared__ float xs[8][128];
    const int t = threadIdx.x;
    const int row0 = blockIdx.x * 8;
    {
        int lr = t >> 5, lc = (t & 31) * 4;
        int row = row0 + lr;
        float4 v = make_float4(0.f, 0.f, 0.f, 0.f);
        if (row < n_rows) v = *(const float4*)(in + (size_t)row * 128 + lc);
        if (RELUIN) {
            v.x = fmaxf(v.x, 0.f); v.y = fmaxf(v.y, 0.f);
            v.z = fmaxf(v.z, 0.f); v.w = fmaxf(v.w, 0.f);
        }
        *(float4*)&xs[lr][lc] = v;
    }
    __syncthreads();
    const int r = t >> 5, c4 = (t & 31) * 4;
    float4 acc = make_float4(0.f, 0.f, 0.f, 0.f);
    #pragma unroll 8
    for (int k = 0; k < 128; ++k) {
        float xv = xs[r][k];
        float4 w = *(const float4*)(W + (size_t)k * 128 + c4);
        acc.x += xv * w.x; acc.y += xv * w.y; acc.z += xv * w.z; acc.w += xv * w.w;
    }
    int row = row0 + r;
    if (row < n_rows) *(float4*)(out + (size_t)row * 128 + c4) = acc;
}

// out[row][0:32] = relu(in[row][0:128]) @ W[128][32]
template<bool RELUIN>
__global__ void gemm_k128_n32(const float* __restrict__ in, const float* __restrict__ W,
                              float* __restrict__ out, int n_rows) {
    __shared__ float xs[8][128];
    const int t = threadIdx.x;
    const int row0 = blockIdx.x * 8;
    {
        int lr = t >> 5, lc = (t & 31) * 4;
        int row = row0 + lr;
        float4 v = make_float4(0.f, 0.f, 0.f, 0.f);
        if (row < n_rows) v = *(const float4*)(in + (size_t)row * 128 + lc);
        if (RELUIN) {
            v.x = fmaxf(v.x, 0.f); v.y = fmaxf(v.y, 0.f);
            v.z = fmaxf(v.z, 0.f); v.w = fmaxf(v.w, 0.f);
        }
        *(float4*)&xs[lr][lc] = v;
    }
    __syncthreads();
    const int r = t >> 5, c = t & 31;
    float acc = 0.f;
    #pragma unroll 8
    for (int k = 0; k < 128; ++k) acc += xs[r][k] * W[(size_t)k * 32 + c];
    int row = row0 + r;
    if (row < n_rows) out[(size_t)row * 32 + c] = acc;
}

// out[row][0:32] = relu(in[row][0:32]) @ W[32][32]
template<bool RELUIN>
__global__ void gemm_k32_n32(const float* __restrict__ in, const float* __restrict__ W,
                             float* __restrict__ out, int n_rows) {
    __shared__ float xs[8][32];
    const int t = threadIdx.x;
    const int row0 = blockIdx.x * 8;
    {
        int lr = t >> 5, lc = t & 31;
        int row = row0 + lr;
        float v = 0.f;
        if (row < n_rows) v = in[(size_t)row * 32 + lc];
        if (RELUIN) v = fmaxf(v, 0.f);
        xs[lr][lc] = v;
    }
    __syncthreads();
    const int r = t >> 5, c = t & 31;
    float acc = 0.f;
    #pragma unroll
    for (int k = 0; k < 32; ++k) acc += xs[r][k] * W[(size_t)k * 32 + c];
    int row = row0 + r;
    if (row < n_rows) out[(size_t)row * 32 + c] = acc;
}

// ---------------- aggregation: agg[d] = b + selfloop + sum_e norm*h[src] ----------------

// init: agg[i][:] = b[:] + h[i][:] * dis[i]^2   (also fully overwrites poisoned ws)
template<int N>
__global__ void agg_init_k(const float* __restrict__ h, const float* __restrict__ dis,
                           const float* __restrict__ b, float* __restrict__ agg, int n) {
    const int Q = N / 4;
    int t = blockIdx.x * blockDim.x + threadIdx.x;
    int i = t / Q, q = (t % Q) * 4;
    if (i >= n) return;
    float d = dis[i];
    float sl = d * d;
    float4 v = *(const float4*)(h + (size_t)i * N + q);
    float4 bb = *(const float4*)(b + q);
    float4 o = make_float4(bb.x + v.x * sl, bb.y + v.y * sl,
                           bb.z + v.z * sl, bb.w + v.w * sl);
    *(float4*)(agg + (size_t)i * N + q) = o;
}

// edges: one thread per (edge, 4-feature-quad)
template<int N>
__global__ void edge_agg_k(const int* __restrict__ src, const int* __restrict__ dst,
                           const float* __restrict__ dis, const float* __restrict__ h,
                           float* __restrict__ agg, int ne) {
    const int Q = N / 4;
    int t = blockIdx.x * blockDim.x + threadIdx.x;
    int e = t / Q, q = (t % Q) * 4;
    if (e >= ne) return;
    int s = src[e], d = dst[e];
    float nrm = dis[s] * dis[d];
    float4 v = *(const float4*)(h + (size_t)s * N + q);
    float* base = agg + (size_t)d * N + q;
    atomicAdd(base + 0, v.x * nrm);
    atomicAdd(base + 1, v.y * nrm);
    atomicAdd(base + 2, v.z * nrm);
    atomicAdd(base + 3, v.w * nrm);
}

// ---------------- head: logits -> log_softmax + softmax ----------------

__global__ void head_k(const float* __restrict__ g3, const int* __restrict__ sel,
                       const float* __restrict__ Wl, const float* __restrict__ bl,
                       float* __restrict__ out, int n_sel) {
    int t = blockIdx.x * blockDim.x + threadIdx.x;
    if (t >= n_sel) return;
    int idx = sel[t];
    const float* g = g3 + (size_t)idx * HID4;
    float l0 = bl[0], l1 = bl[1];
    #pragma unroll
    for (int k = 0; k < HID4; ++k) {
        float gv = g[k];
        l0 += gv * Wl[k * 2 + 0];
        l1 += gv * Wl[k * 2 + 1];
    }
    float m = fmaxf(l0, l1);
    float e0 = expf(l0 - m), e1 = expf(l1 - m);
    float s = e0 + e1;
    float ls = logf(s);
    // lsm (n_sel x 2) then softmax (n_sel x 2), row-major flat
    out[t * 2 + 0] = (l0 - m) - ls;
    out[t * 2 + 1] = (l1 - m) - ls;
    out[2 * n_sel + t * 2 + 0] = e0 / s;
    out[2 * n_sel + t * 2 + 1] = e1 / s;
}

// ---------------- launch ----------------

extern "C" void kernel_launch(void* const* d_in, const int* in_sizes, int n_in,
                              void* d_out, int out_size, void* d_ws, size_t ws_size,
                              hipStream_t stream) {
    const float* x  = (const float*)d_in[0];
    const int* edge = (const int*)d_in[1];
    const int* sel  = (const int*)d_in[2];
    // d_in[3] = labels (only used for slicing length; == n_sel)
    const float* W1 = (const float*)d_in[4];
    const float* b1 = (const float*)d_in[5];
    const float* W2 = (const float*)d_in[6];
    const float* b2 = (const float*)d_in[7];
    const float* W3 = (const float*)d_in[8];
    const float* b3 = (const float*)d_in[9];
    const float* Wl = (const float*)d_in[10];
    const float* bl = (const float*)d_in[11];
    float* out = (float*)d_out;

    const int n_nodes = in_sizes[0] / F_IN;
    const int n_edges = in_sizes[1] / 2;
    const int n_sel   = in_sizes[2];
    const int* srcv = edge;
    const int* dstv = edge + n_edges;

    char* ws = (char*)d_ws;
    int*   deg  = (int*)ws;   ws += alignup((size_t)n_nodes * 4);
    float* dis  = (float*)ws; ws += alignup((size_t)n_nodes * 4);
    float* bufA = (float*)ws; ws += alignup((size_t)n_nodes * HID * 4);
    float* bufB = (float*)ws;

    const int B = 256;
    #define GRD(n) (((n) + B - 1) / B)

    // normalization
    deg_init_k<<<GRD(n_nodes), B, 0, stream>>>(deg, n_nodes);
    deg_count_k<<<GRD(n_edges), B, 0, stream>>>(dstv, deg, n_edges);
    dis_k<<<GRD(n_nodes), B, 0, stream>>>(deg, dis, n_nodes);

    const int gemm_blocks = (n_nodes + 7) / 8;

    // layer 1: h1 = x @ W1 (bufA); agg1 = A h1 + b1 (bufB)
    gemm_k128_n128<false><<<gemm_blocks, B, 0, stream>>>(x, W1, bufA, n_nodes);
    agg_init_k<HID><<<GRD(n_nodes * (HID / 4)), B, 0, stream>>>(bufA, dis, b1, bufB, n_nodes);
    edge_agg_k<HID><<<GRD(n_edges * (HID / 4)), B, 0, stream>>>(srcv, dstv, dis, bufA, bufB, n_edges);

    // layer 2: h2 = relu(agg1) @ W2 (bufA); agg2 = A h2 + b2 (bufB)
    gemm_k128_n32<true><<<gemm_blocks, B, 0, stream>>>(bufB, W2, bufA, n_nodes);
    agg_init_k<HID4><<<GRD(n_nodes * (HID4 / 4)), B, 0, stream>>>(bufA, dis, b2, bufB, n_nodes);
    edge_agg_k<HID4><<<GRD(n_edges * (HID4 / 4)), B, 0, stream>>>(srcv, dstv, dis, bufA, bufB, n_edges);

    // layer 3: h3 = relu(agg2) @ W3 (bufA); agg3 = A h3 + b3 (bufB)
    gemm_k32_n32<true><<<gemm_blocks, B, 0, stream>>>(bufB, W3, bufA, n_nodes);
    agg_init_k<HID4><<<GRD(n_nodes * (HID4 / 4)), B, 0, stream>>>(bufA, dis, b3, bufB, n_nodes);
    edge_agg_k<HID4><<<GRD(n_edges * (HID4 / 4)), B, 0, stream>>>(srcv, dstv, dis, bufA, bufB, n_edges);

    // head
    head_k<<<GRD(n_sel), B, 0, stream>>>(bufB, sel, Wl, bl, out, n_sel);

    #undef GRD
}

// Round 2
// 418.887 us; speedup vs baseline: 5.2428x; 5.2428x over previous
//
#include <hip/hip_runtime.h>

#define F_IN 128
#define HID 128
#define HID4 32

static inline size_t alignup(size_t x) { return (x + 255) & ~(size_t)255; }

// ---------------- degree / normalization ----------------

__global__ void deg_init_k(int* __restrict__ deg, int n) {
    int i = blockIdx.x * blockDim.x + threadIdx.x;
    if (i < n) deg[i] = 0;  // edge-only in-degree; self-loop added analytically
}

__global__ void deg_count_k(const int* __restrict__ dst, int* __restrict__ deg, int ne) {
    int e = blockIdx.x * blockDim.x + threadIdx.x;
    if (e < ne) atomicAdd(&deg[dst[e]], 1);
}

__global__ void dis_k(const int* __restrict__ deg, float* __restrict__ dis, int n) {
    int i = blockIdx.x * blockDim.x + threadIdx.x;
    if (i < n) dis[i] = rsqrtf((float)(deg[i] + 1));  // +1 self-loop, always > 0
}

// ---------------- exclusive scan of deg -> rowoff (3 kernels) ----------------

__global__ void scan_block_k(const int* __restrict__ deg, int* __restrict__ rowoff,
                             int* __restrict__ partials, int n) {
    __shared__ int tmp[256];
    int i = blockIdx.x * 256 + threadIdx.x;
    int v = (i < n) ? deg[i] : 0;
    tmp[threadIdx.x] = v;
    __syncthreads();
    for (int off = 1; off < 256; off <<= 1) {
        int t = (threadIdx.x >= off) ? tmp[threadIdx.x - off] : 0;
        __syncthreads();
        tmp[threadIdx.x] += t;
        __syncthreads();
    }
    if (i < n) rowoff[i] = tmp[threadIdx.x] - v;  // exclusive within block
    if (threadIdx.x == 255) partials[blockIdx.x] = tmp[255];
}

__global__ void scan_partials_k(int* __restrict__ partials, int nb) {
    __shared__ int tmp[256];
    int v = (threadIdx.x < nb) ? partials[threadIdx.x] : 0;
    tmp[threadIdx.x] = v;
    __syncthreads();
    for (int off = 1; off < 256; off <<= 1) {
        int t = (threadIdx.x >= off) ? tmp[threadIdx.x - off] : 0;
        __syncthreads();
        tmp[threadIdx.x] += t;
        __syncthreads();
    }
    if (threadIdx.x < nb) partials[threadIdx.x] = tmp[threadIdx.x] - v;  // exclusive
}

__global__ void add_offsets_k(int* __restrict__ rowoff, int* __restrict__ cursor,
                              const int* __restrict__ partials, int n) {
    int i = blockIdx.x * 256 + threadIdx.x;
    if (i < n) {
        int r = rowoff[i] + partials[i >> 8];
        rowoff[i] = r;
        cursor[i] = r;
    }
}

// ---------------- scatter edges into CSR order ----------------

__global__ void scatter_k(const int* __restrict__ src, const int* __restrict__ dst,
                          int* __restrict__ cursor, int* __restrict__ csr_src, int ne) {
    int e = blockIdx.x * blockDim.x + threadIdx.x;
    if (e >= ne) return;
    int d = dst[e];
    int pos = atomicAdd(&cursor[d], 1);
    csr_src[pos] = src[e];
}
// after scatter: cursor[d] == rowoff[d] + indeg(d)  -> serves as row end

// ---------------- GEMMs (fp32 vector ALU; no fp32 MFMA on CDNA4) ----------------

template<bool RELUIN>
__global__ void gemm_k128_n128(const float* __restrict__ in, const float* __restrict__ W,
                               float* __restrict__ out, int n_rows) {
    __shared__ float xs[8][128];
    const int t = threadIdx.x;
    const int row0 = blockIdx.x * 8;
    {
        int lr = t >> 5, lc = (t & 31) * 4;
        int row = row0 + lr;
        float4 v = make_float4(0.f, 0.f, 0.f, 0.f);
        if (row < n_rows) v = *(const float4*)(in + (size_t)row * 128 + lc);
        if (RELUIN) {
            v.x = fmaxf(v.x, 0.f); v.y = fmaxf(v.y, 0.f);
            v.z = fmaxf(v.z, 0.f); v.w = fmaxf(v.w, 0.f);
        }
        *(float4*)&xs[lr][lc] = v;
    }
    __syncthreads();
    const int r = t >> 5, c4 = (t & 31) * 4;
    float4 acc = make_float4(0.f, 0.f, 0.f, 0.f);
    #pragma unroll 8
    for (int k = 0; k < 128; ++k) {
        float xv = xs[r][k];
        float4 w = *(const float4*)(W + (size_t)k * 128 + c4);
        acc.x += xv * w.x; acc.y += xv * w.y; acc.z += xv * w.z; acc.w += xv * w.w;
    }
    int row = row0 + r;
    if (row < n_rows) *(float4*)(out + (size_t)row * 128 + c4) = acc;
}

template<bool RELUIN>
__global__ void gemm_k128_n32(const float* __restrict__ in, const float* __restrict__ W,
                              float* __restrict__ out, int n_rows) {
    __shared__ float xs[8][128];
    const int t = threadIdx.x;
    const int row0 = blockIdx.x * 8;
    {
        int lr = t >> 5, lc = (t & 31) * 4;
        int row = row0 + lr;
        float4 v = make_float4(0.f, 0.f, 0.f, 0.f);
        if (row < n_rows) v = *(const float4*)(in + (size_t)row * 128 + lc);
        if (RELUIN) {
            v.x = fmaxf(v.x, 0.f); v.y = fmaxf(v.y, 0.f);
            v.z = fmaxf(v.z, 0.f); v.w = fmaxf(v.w, 0.f);
        }
        *(float4*)&xs[lr][lc] = v;
    }
    __syncthreads();
    const int r = t >> 5, c = t & 31;
    float acc = 0.f;
    #pragma unroll 8
    for (int k = 0; k < 128; ++k) acc += xs[r][k] * W[(size_t)k * 32 + c];
    int row = row0 + r;
    if (row < n_rows) out[(size_t)row * 32 + c] = acc;
}

template<bool RELUIN>
__global__ void gemm_k32_n32(const float* __restrict__ in, const float* __restrict__ W,
                             float* __restrict__ out, int n_rows) {
    __shared__ float xs[8][32];
    const int t = threadIdx.x;
    const int row0 = blockIdx.x * 8;
    {
        int lr = t >> 5, lc = t & 31;
        int row = row0 + lr;
        float v = 0.f;
        if (row < n_rows) v = in[(size_t)row * 32 + lc];
        if (RELUIN) v = fmaxf(v, 0.f);
        xs[lr][lc] = v;
    }
    __syncthreads();
    const int r = t >> 5, c = t & 31;
    float acc = 0.f;
    #pragma unroll
    for (int k = 0; k < 32; ++k) acc += xs[r][k] * W[(size_t)k * 32 + c];
    int row = row0 + r;
    if (row < n_rows) out[(size_t)row * 32 + c] = acc;
}

// ---------------- pull aggregation (no atomics) ----------------
// out[d][:] = b + dis[d] * ( dis[d]*h[d][:] + sum_{e: dst=d} dis[src]*h[src][:] )

template<int N, int TPN>  // TPN threads per node; VPT = N/TPN contiguous floats per thread
__global__ void pull_k(const float* __restrict__ h, const int* __restrict__ rowoff,
                       const int* __restrict__ rowend, const int* __restrict__ csr_src,
                       const float* __restrict__ dis, const float* __restrict__ b,
                       float* __restrict__ out, int n_nodes) {
    constexpr int VPT = N / TPN;
    int gt = blockIdx.x * blockDim.x + threadIdx.x;
    int node = gt / TPN;
    int f0 = (gt % TPN) * VPT;
    if (node >= n_nodes) return;
    int beg = rowoff[node];
    int end = rowend[node];
    float dd = dis[node];

    float acc[VPT];
    const float* hd = h + (size_t)node * N + f0;
    #pragma unroll
    for (int v = 0; v < VPT; ++v) acc[v] = dd * hd[v];  // self-loop (dd applied again below)

    for (int j = beg; j < end; ++j) {
        int s = csr_src[j];
        float w = dis[s];
        const float* hs = h + (size_t)s * N + f0;
        #pragma unroll
        for (int v = 0; v < VPT; ++v) acc[v] += w * hs[v];
    }

    float* o = out + (size_t)node * N + f0;
    #pragma unroll
    for (int v = 0; v < VPT; ++v) o[v] = b[f0 + v] + dd * acc[v];
}

// ---------------- head: logits -> log_softmax + softmax ----------------

__global__ void head_k(const float* __restrict__ g3, const int* __restrict__ sel,
                       const float* __restrict__ Wl, const float* __restrict__ bl,
                       float* __restrict__ out, int n_sel) {
    int t = blockIdx.x * blockDim.x + threadIdx.x;
    if (t >= n_sel) return;
    int idx = sel[t];
    const float* g = g3 + (size_t)idx * HID4;
    float l0 = bl[0], l1 = bl[1];
    #pragma unroll
    for (int k = 0; k < HID4; ++k) {
        float gv = g[k];
        l0 += gv * Wl[k * 2 + 0];
        l1 += gv * Wl[k * 2 + 1];
    }
    float m = fmaxf(l0, l1);
    float e0 = expf(l0 - m), e1 = expf(l1 - m);
    float s = e0 + e1;
    float ls = logf(s);
    out[t * 2 + 0] = (l0 - m) - ls;
    out[t * 2 + 1] = (l1 - m) - ls;
    out[2 * n_sel + t * 2 + 0] = e0 / s;
    out[2 * n_sel + t * 2 + 1] = e1 / s;
}

// ---------------- launch ----------------

extern "C" void kernel_launch(void* const* d_in, const int* in_sizes, int n_in,
                              void* d_out, int out_size, void* d_ws, size_t ws_size,
                              hipStream_t stream) {
    const float* x  = (const float*)d_in[0];
    const int* edge = (const int*)d_in[1];
    const int* sel  = (const int*)d_in[2];
    const float* W1 = (const float*)d_in[4];
    const float* b1 = (const float*)d_in[5];
    const float* W2 = (const float*)d_in[6];
    const float* b2 = (const float*)d_in[7];
    const float* W3 = (const float*)d_in[8];
    const float* b3 = (const float*)d_in[9];
    const float* Wl = (const float*)d_in[10];
    const float* bl = (const float*)d_in[11];
    float* out = (float*)d_out;

    const int n_nodes = in_sizes[0] / F_IN;
    const int n_edges = in_sizes[1] / 2;
    const int n_sel   = in_sizes[2];
    const int* srcv = edge;
    const int* dstv = edge + n_edges;

    char* ws = (char*)d_ws;
    int*   deg      = (int*)ws;   ws += alignup((size_t)n_nodes * 4);
    float* dis      = (float*)ws; ws += alignup((size_t)n_nodes * 4);
    int*   rowoff   = (int*)ws;   ws += alignup((size_t)n_nodes * 4);
    int*   cursor   = (int*)ws;   ws += alignup((size_t)n_nodes * 4);
    int*   partials = (int*)ws;   ws += alignup(1024);
    int*   csr_src  = (int*)ws;   ws += alignup((size_t)n_edges * 4);
    float* bufA     = (float*)ws; ws += alignup((size_t)n_nodes * HID * 4);
    float* bufB     = (float*)ws;

    const int B = 256;
    #define GRD(n) (((n) + B - 1) / B)
    const int nblk = GRD(n_nodes);  // blocks over nodes (also partials count)

    // normalization + CSR build (reused by all 3 layers)
    deg_init_k<<<nblk, B, 0, stream>>>(deg, n_nodes);
    deg_count_k<<<GRD(n_edges), B, 0, stream>>>(dstv, deg, n_edges);
    dis_k<<<nblk, B, 0, stream>>>(deg, dis, n_nodes);
    scan_block_k<<<nblk, B, 0, stream>>>(deg, rowoff, partials, n_nodes);
    scan_partials_k<<<1, B, 0, stream>>>(partials, nblk);
    add_offsets_k<<<nblk, B, 0, stream>>>(rowoff, cursor, partials, n_nodes);
    scatter_k<<<GRD(n_edges), B, 0, stream>>>(srcv, dstv, cursor, csr_src, n_edges);

    const int gemm_blocks = (n_nodes + 7) / 8;

    // layer 1: h1 = x @ W1 (bufA); agg1 = Â h1 + b1 (bufB)
    gemm_k128_n128<false><<<gemm_blocks, B, 0, stream>>>(x, W1, bufA, n_nodes);
    pull_k<HID, 64><<<GRD(n_nodes * 64), B, 0, stream>>>(bufA, rowoff, cursor, csr_src, dis, b1, bufB, n_nodes);

    // layer 2: h2 = relu(agg1) @ W2 (bufA); agg2 = Â h2 + b2 (bufB)
    gemm_k128_n32<true><<<gemm_blocks, B, 0, stream>>>(bufB, W2, bufA, n_nodes);
    pull_k<HID4, 32><<<GRD(n_nodes * 32), B, 0, stream>>>(bufA, rowoff, cursor, csr_src, dis, b2, bufB, n_nodes);

    // layer 3: h3 = relu(agg2) @ W3 (bufA); agg3 = Â h3 + b3 (bufB)
    gemm_k32_n32<true><<<gemm_blocks, B, 0, stream>>>(bufB, W3, bufA, n_nodes);
    pull_k<HID4, 32><<<GRD(n_nodes * 32), B, 0, stream>>>(bufA, rowoff, cursor, csr_src, dis, b3, bufB, n_nodes);

    // head
    head_k<<<GRD(n_sel), B, 0, stream>>>(bufB, sel, Wl, bl, out, n_sel);

    #undef GRD
}

// Round 3
// 262.526 us; speedup vs baseline: 8.3655x; 1.5956x over previous
//
#include <hip/hip_runtime.h>

#define F_IN 128
#define HID 128
#define HID4 32

static inline size_t alignup(size_t x) { return (x + 255) & ~(size_t)255; }

// ---------------- degree / normalization ----------------

__global__ void deg_init_k(int* __restrict__ deg, int n) {
    int i = blockIdx.x * blockDim.x + threadIdx.x;
    if (i < n) deg[i] = 0;  // edge-only in-degree; self-loop added analytically
}

__global__ void deg_count_k(const int* __restrict__ dst, int* __restrict__ deg, int ne) {
    int e = blockIdx.x * blockDim.x + threadIdx.x;
    if (e < ne) atomicAdd(&deg[dst[e]], 1);
}

__global__ void dis_k(const int* __restrict__ deg, float* __restrict__ dis, int n) {
    int i = blockIdx.x * blockDim.x + threadIdx.x;
    if (i < n) dis[i] = rsqrtf((float)(deg[i] + 1));  // +1 self-loop, always > 0
}

// ---------------- exclusive scan of deg -> rowoff ----------------

__global__ void scan_block_k(const int* __restrict__ deg, int* __restrict__ rowoff,
                             int* __restrict__ partials, int n) {
    __shared__ int tmp[256];
    int i = blockIdx.x * 256 + threadIdx.x;
    int v = (i < n) ? deg[i] : 0;
    tmp[threadIdx.x] = v;
    __syncthreads();
    for (int off = 1; off < 256; off <<= 1) {
        int t = (threadIdx.x >= off) ? tmp[threadIdx.x - off] : 0;
        __syncthreads();
        tmp[threadIdx.x] += t;
        __syncthreads();
    }
    if (i < n) rowoff[i] = tmp[threadIdx.x] - v;
    if (threadIdx.x == 255) partials[blockIdx.x] = tmp[255];
}

__global__ void scan_partials_k(int* __restrict__ partials, int nb) {
    __shared__ int tmp[256];
    int v = (threadIdx.x < nb) ? partials[threadIdx.x] : 0;
    tmp[threadIdx.x] = v;
    __syncthreads();
    for (int off = 1; off < 256; off <<= 1) {
        int t = (threadIdx.x >= off) ? tmp[threadIdx.x - off] : 0;
        __syncthreads();
        tmp[threadIdx.x] += t;
        __syncthreads();
    }
    if (threadIdx.x < nb) partials[threadIdx.x] = tmp[threadIdx.x] - v;
}

__global__ void add_offsets_k(int* __restrict__ rowoff, int* __restrict__ cursor,
                              const int* __restrict__ partials, int n) {
    int i = blockIdx.x * 256 + threadIdx.x;
    if (i < n) {
        int r = rowoff[i] + partials[i >> 8];
        rowoff[i] = r;
        cursor[i] = r;
    }
}

// ---------------- scatter edges into CSR order, packing (src, dis[src]) ----------------

__global__ void scatter_k(const int* __restrict__ src, const int* __restrict__ dst,
                          const float* __restrict__ dis,
                          int* __restrict__ cursor, int2* __restrict__ csr, int ne) {
    int e = blockIdx.x * blockDim.x + threadIdx.x;
    if (e >= ne) return;
    int s = src[e];
    int d = dst[e];
    int pos = atomicAdd(&cursor[d], 1);
    csr[pos] = make_int2(s, __float_as_int(dis[s]));
}
// after scatter: cursor[d] == rowoff[d] + indeg(d)  -> row end

// ---------------- GEMM1: out[n][128] = in[n][128] @ W[128][128] ----------------
// 64 rows/block, 256 threads, acc 4x8/thread. LDS: xs 33.8KB + wt 16KB (k-tiled).

__global__ __launch_bounds__(256) void gemm1_k(const float* __restrict__ in,
                                               const float* __restrict__ W,
                                               float* __restrict__ out, int n_rows) {
    __shared__ float xs[64][132];
    __shared__ float wt[32][128];
    const int t = threadIdx.x;
    const int row0 = blockIdx.x * 64;

    // stage x rows (8 float4 per thread)
    #pragma unroll
    for (int i = 0; i < 8; ++i) {
        int q = t + i * 256;
        int row = q >> 5, c4 = (q & 31) * 4;
        float4 v = make_float4(0.f, 0.f, 0.f, 0.f);
        if (row0 + row < n_rows) v = *(const float4*)(in + (size_t)(row0 + row) * 128 + c4);
        *(float4*)&xs[row][c4] = v;
    }

    const int cg = t & 15;        // 16 col groups
    const int c4a = cg * 4;       // cols c4a..c4a+3 and 64+c4a..64+c4a+3
    const int r4 = (t >> 4) * 4;  // 4 rows

    float acc[4][8];
    #pragma unroll
    for (int i = 0; i < 4; ++i)
        #pragma unroll
        for (int j = 0; j < 8; ++j) acc[i][j] = 0.f;

    for (int kt = 0; kt < 4; ++kt) {
        __syncthreads();
        // stage W k-tile (4 float4 per thread)
        #pragma unroll
        for (int i = 0; i < 4; ++i) {
            int q = t + i * 256;
            int kk = q >> 5, c4 = (q & 31) * 4;
            *(float4*)&wt[kk][c4] = *(const float4*)(W + (size_t)(kt * 32 + kk) * 128 + c4);
        }
        __syncthreads();
        #pragma unroll 4
        for (int k = 0; k < 32; ++k) {
            float xv[4];
            #pragma unroll
            for (int i = 0; i < 4; ++i) xv[i] = xs[r4 + i][kt * 32 + k];
            float4 w0 = *(float4*)&wt[k][c4a];
            float4 w1 = *(float4*)&wt[k][64 + c4a];
            #pragma unroll
            for (int i = 0; i < 4; ++i) {
                acc[i][0] += xv[i] * w0.x; acc[i][1] += xv[i] * w0.y;
                acc[i][2] += xv[i] * w0.z; acc[i][3] += xv[i] * w0.w;
                acc[i][4] += xv[i] * w1.x; acc[i][5] += xv[i] * w1.y;
                acc[i][6] += xv[i] * w1.z; acc[i][7] += xv[i] * w1.w;
            }
        }
    }

    #pragma unroll
    for (int i = 0; i < 4; ++i) {
        int row = row0 + r4 + i;
        if (row < n_rows) {
            *(float4*)(out + (size_t)row * 128 + c4a) =
                make_float4(acc[i][0], acc[i][1], acc[i][2], acc[i][3]);
            *(float4*)(out + (size_t)row * 128 + 64 + c4a) =
                make_float4(acc[i][4], acc[i][5], acc[i][6], acc[i][7]);
        }
    }
}

// ---------------- GEMM2: out[n][32] = relu(in[n][128]) @ W[128][32] ----------------
// 64 rows/block, 256 threads, acc 2x4/thread.

__global__ __launch_bounds__(256) void gemm2_k(const float* __restrict__ in,
                                               const float* __restrict__ W,
                                               float* __restrict__ out, int n_rows) {
    __shared__ float xs[64][132];
    __shared__ float wt[128][32];
    const int t = threadIdx.x;
    const int row0 = blockIdx.x * 64;

    #pragma unroll
    for (int i = 0; i < 8; ++i) {
        int q = t + i * 256;
        int row = q >> 5, c4 = (q & 31) * 4;
        float4 v = make_float4(0.f, 0.f, 0.f, 0.f);
        if (row0 + row < n_rows) {
            v = *(const float4*)(in + (size_t)(row0 + row) * 128 + c4);
            v.x = fmaxf(v.x, 0.f); v.y = fmaxf(v.y, 0.f);
            v.z = fmaxf(v.z, 0.f); v.w = fmaxf(v.w, 0.f);
        }
        *(float4*)&xs[row][c4] = v;
    }
    #pragma unroll
    for (int i = 0; i < 4; ++i) {
        int q = t + i * 256;
        int kk = q >> 3, c4 = (q & 7) * 4;
        *(float4*)&wt[kk][c4] = *(const float4*)(W + (size_t)kk * 32 + c4);
    }
    __syncthreads();

    const int c4 = (t & 7) * 4;
    const int r2 = (t >> 3) * 2;

    float acc[2][4];
    #pragma unroll
    for (int i = 0; i < 2; ++i)
        #pragma unroll
        for (int j = 0; j < 4; ++j) acc[i][j] = 0.f;

    #pragma unroll 4
    for (int k = 0; k < 128; ++k) {
        float x0 = xs[r2][k], x1 = xs[r2 + 1][k];
        float4 w = *(float4*)&wt[k][c4];
        acc[0][0] += x0 * w.x; acc[0][1] += x0 * w.y; acc[0][2] += x0 * w.z; acc[0][3] += x0 * w.w;
        acc[1][0] += x1 * w.x; acc[1][1] += x1 * w.y; acc[1][2] += x1 * w.z; acc[1][3] += x1 * w.w;
    }

    #pragma unroll
    for (int i = 0; i < 2; ++i) {
        int row = row0 + r2 + i;
        if (row < n_rows)
            *(float4*)(out + (size_t)row * 32 + c4) =
                make_float4(acc[i][0], acc[i][1], acc[i][2], acc[i][3]);
    }
}

// ---------------- GEMM3: out[n][32] = relu(in[n][32]) @ W[32][32] ----------------

__global__ __launch_bounds__(256) void gemm3_k(const float* __restrict__ in,
                                               const float* __restrict__ W,
                                               float* __restrict__ out, int n_rows) {
    __shared__ float xs[64][36];
    __shared__ float wt[32][32];
    const int t = threadIdx.x;
    const int row0 = blockIdx.x * 64;

    #pragma unroll
    for (int i = 0; i < 2; ++i) {
        int q = t + i * 256;
        int row = q >> 3, c4 = (q & 7) * 4;
        float4 v = make_float4(0.f, 0.f, 0.f, 0.f);
        if (row0 + row < n_rows) {
            v = *(const float4*)(in + (size_t)(row0 + row) * 32 + c4);
            v.x = fmaxf(v.x, 0.f); v.y = fmaxf(v.y, 0.f);
            v.z = fmaxf(v.z, 0.f); v.w = fmaxf(v.w, 0.f);
        }
        *(float4*)&xs[row][c4] = v;
    }
    {
        int kk = t >> 3, c4 = (t & 7) * 4;
        *(float4*)&wt[kk][c4] = *(const float4*)(W + (size_t)kk * 32 + c4);
    }
    __syncthreads();

    const int c4 = (t & 7) * 4;
    const int r2 = (t >> 3) * 2;

    float acc[2][4];
    #pragma unroll
    for (int i = 0; i < 2; ++i)
        #pragma unroll
        for (int j = 0; j < 4; ++j) acc[i][j] = 0.f;

    #pragma unroll
    for (int k = 0; k < 32; ++k) {
        float x0 = xs[r2][k], x1 = xs[r2 + 1][k];
        float4 w = *(float4*)&wt[k][c4];
        acc[0][0] += x0 * w.x; acc[0][1] += x0 * w.y; acc[0][2] += x0 * w.z; acc[0][3] += x0 * w.w;
        acc[1][0] += x1 * w.x; acc[1][1] += x1 * w.y; acc[1][2] += x1 * w.z; acc[1][3] += x1 * w.w;
    }

    #pragma unroll
    for (int i = 0; i < 2; ++i) {
        int row = row0 + r2 + i;
        if (row < n_rows)
            *(float4*)(out + (size_t)row * 32 + c4) =
                make_float4(acc[i][0], acc[i][1], acc[i][2], acc[i][3]);
    }
}

// ---------------- pull aggregation (no atomics, float4 gathers) ----------------
// out[d][:] = b + dis[d] * ( dis[d]*h[d][:] + sum_{e: dst=d} dis[src]*h[src][:] )

template<int N, int TPN>  // VPT = N/TPN = 4
__global__ void pull_k(const float* __restrict__ h, const int* __restrict__ rowoff,
                       const int* __restrict__ rowend, const int2* __restrict__ csr,
                       const float* __restrict__ dis, const float* __restrict__ b,
                       float* __restrict__ out, int n_nodes) {
    int gt = blockIdx.x * blockDim.x + threadIdx.x;
    int node = gt / TPN;
    int f0 = (gt % TPN) * 4;
    if (node >= n_nodes) return;
    int beg = rowoff[node];
    int end = rowend[node];
    float dd = dis[node];

    float4 acc = *(const float4*)(h + (size_t)node * N + f0);
    acc.x *= dd; acc.y *= dd; acc.z *= dd; acc.w *= dd;  // self-loop (dd applied again below)

    for (int j = beg; j < end; ++j) {
        int2 sw = csr[j];
        float w = __int_as_float(sw.y);
        float4 hs = *(const float4*)(h + (size_t)sw.x * N + f0);
        acc.x += w * hs.x; acc.y += w * hs.y; acc.z += w * hs.z; acc.w += w * hs.w;
    }

    float4 bb = *(const float4*)(b + f0);
    float4 o = make_float4(bb.x + dd * acc.x, bb.y + dd * acc.y,
                           bb.z + dd * acc.z, bb.w + dd * acc.w);
    *(float4*)(out + (size_t)node * N + f0) = o;
}

// ---------------- head: logits -> log_softmax + softmax ----------------

__global__ void head_k(const float* __restrict__ g3, const int* __restrict__ sel,
                       const float* __restrict__ Wl, const float* __restrict__ bl,
                       float* __restrict__ out, int n_sel) {
    int t = blockIdx.x * blockDim.x + threadIdx.x;
    if (t >= n_sel) return;
    int idx = sel[t];
    const float* g = g3 + (size_t)idx * HID4;
    float l0 = bl[0], l1 = bl[1];
    #pragma unroll
    for (int k = 0; k < HID4; ++k) {
        float gv = g[k];
        l0 += gv * Wl[k * 2 + 0];
        l1 += gv * Wl[k * 2 + 1];
    }
    float m = fmaxf(l0, l1);
    float e0 = expf(l0 - m), e1 = expf(l1 - m);
    float s = e0 + e1;
    float ls = logf(s);
    out[t * 2 + 0] = (l0 - m) - ls;
    out[t * 2 + 1] = (l1 - m) - ls;
    out[2 * n_sel + t * 2 + 0] = e0 / s;
    out[2 * n_sel + t * 2 + 1] = e1 / s;
}

// ---------------- launch ----------------

extern "C" void kernel_launch(void* const* d_in, const int* in_sizes, int n_in,
                              void* d_out, int out_size, void* d_ws, size_t ws_size,
                              hipStream_t stream) {
    const float* x  = (const float*)d_in[0];
    const int* edge = (const int*)d_in[1];
    const int* sel  = (const int*)d_in[2];
    const float* W1 = (const float*)d_in[4];
    const float* b1 = (const float*)d_in[5];
    const float* W2 = (const float*)d_in[6];
    const float* b2 = (const float*)d_in[7];
    const float* W3 = (const float*)d_in[8];
    const float* b3 = (const float*)d_in[9];
    const float* Wl = (const float*)d_in[10];
    const float* bl = (const float*)d_in[11];
    float* out = (float*)d_out;

    const int n_nodes = in_sizes[0] / F_IN;
    const int n_edges = in_sizes[1] / 2;
    const int n_sel   = in_sizes[2];
    const int* srcv = edge;
    const int* dstv = edge + n_edges;

    char* ws = (char*)d_ws;
    int*   deg      = (int*)ws;   ws += alignup((size_t)n_nodes * 4);
    float* dis      = (float*)ws; ws += alignup((size_t)n_nodes * 4);
    int*   rowoff   = (int*)ws;   ws += alignup((size_t)n_nodes * 4);
    int*   cursor   = (int*)ws;   ws += alignup((size_t)n_nodes * 4);
    int*   partials = (int*)ws;   ws += alignup(1024);
    int2*  csr      = (int2*)ws;  ws += alignup((size_t)n_edges * 8);
    float* bufA     = (float*)ws; ws += alignup((size_t)n_nodes * HID * 4);
    float* bufB     = (float*)ws;

    const int B = 256;
    #define GRD(n) (((n) + B - 1) / B)
    const int nblk = GRD(n_nodes);

    // normalization + CSR build (reused by all 3 layers)
    deg_init_k<<<nblk, B, 0, stream>>>(deg, n_nodes);
    deg_count_k<<<GRD(n_edges), B, 0, stream>>>(dstv, deg, n_edges);
    dis_k<<<nblk, B, 0, stream>>>(deg, dis, n_nodes);
    scan_block_k<<<nblk, B, 0, stream>>>(deg, rowoff, partials, n_nodes);
    scan_partials_k<<<1, B, 0, stream>>>(partials, nblk);
    add_offsets_k<<<nblk, B, 0, stream>>>(rowoff, cursor, partials, n_nodes);
    scatter_k<<<GRD(n_edges), B, 0, stream>>>(srcv, dstv, dis, cursor, csr, n_edges);

    const int gemm_blocks = (n_nodes + 63) / 64;

    // layer 1
    gemm1_k<<<gemm_blocks, B, 0, stream>>>(x, W1, bufA, n_nodes);
    pull_k<HID, 32><<<GRD(n_nodes * 32), B, 0, stream>>>(bufA, rowoff, cursor, csr, dis, b1, bufB, n_nodes);

    // layer 2
    gemm2_k<<<gemm_blocks, B, 0, stream>>>(bufB, W2, bufA, n_nodes);
    pull_k<HID4, 8><<<GRD(n_nodes * 8), B, 0, stream>>>(bufA, rowoff, cursor, csr, dis, b2, bufB, n_nodes);

    // layer 3
    gemm3_k<<<gemm_blocks, B, 0, stream>>>(bufB, W3, bufA, n_nodes);
    pull_k<HID4, 8><<<GRD(n_nodes * 8), B, 0, stream>>>(bufA, rowoff, cursor, csr, dis, b3, bufB, n_nodes);

    // head
    head_k<<<GRD(n_sel), B, 0, stream>>>(bufB, sel, Wl, bl, out, n_sel);

    #undef GRD
}

// Round 4
// 214.435 us; speedup vs baseline: 10.2416x; 1.2243x over previous
//
#include <hip/hip_runtime.h>
#include <hip/hip_fp16.h>

#define F_IN 128
#define HID 128
#define HID4 32

static inline size_t alignup(size_t x) { return (x + 255) & ~(size_t)255; }

union H4 { uint2 u; __half2 h[2]; };      // 4 halfs = 8 B
union F4H8 { float4 f; __half2 h[4]; };   // 8 halfs = 16 B

// ---------------- degree / normalization ----------------

__global__ void deg_count_k(const int* __restrict__ dst, int* __restrict__ deg, int ne) {
    int e = blockIdx.x * blockDim.x + threadIdx.x;
    if (e < ne) atomicAdd(&deg[dst[e]], 1);
}

// ---------------- exclusive scan of deg -> rowoff ----------------

__global__ void scan_block_k(const int* __restrict__ deg, int* __restrict__ rowoff,
                             int* __restrict__ partials, int n) {
    __shared__ int tmp[256];
    int i = blockIdx.x * 256 + threadIdx.x;
    int v = (i < n) ? deg[i] : 0;
    tmp[threadIdx.x] = v;
    __syncthreads();
    for (int off = 1; off < 256; off <<= 1) {
        int t = (threadIdx.x >= off) ? tmp[threadIdx.x - off] : 0;
        __syncthreads();
        tmp[threadIdx.x] += t;
        __syncthreads();
    }
    if (i < n) rowoff[i] = tmp[threadIdx.x] - v;
    if (threadIdx.x == 255) partials[blockIdx.x] = tmp[255];
}

__global__ void scan_partials_k(int* __restrict__ partials, int nb) {
    __shared__ int tmp[256];
    int v = (threadIdx.x < nb) ? partials[threadIdx.x] : 0;
    tmp[threadIdx.x] = v;
    __syncthreads();
    for (int off = 1; off < 256; off <<= 1) {
        int t = (threadIdx.x >= off) ? tmp[threadIdx.x - off] : 0;
        __syncthreads();
        tmp[threadIdx.x] += t;
        __syncthreads();
    }
    if (threadIdx.x < nb) partials[threadIdx.x] = tmp[threadIdx.x] - v;
}

// also computes dis = rsqrt(deg+1)
__global__ void add_offsets_k(const int* __restrict__ deg, float* __restrict__ dis,
                              int* __restrict__ rowoff, int* __restrict__ cursor,
                              const int* __restrict__ partials, int n) {
    int i = blockIdx.x * 256 + threadIdx.x;
    if (i < n) {
        int r = rowoff[i] + partials[i >> 8];
        rowoff[i] = r;
        cursor[i] = r;
        dis[i] = rsqrtf((float)(deg[i] + 1));
    }
}

// ---------------- scatter edges into CSR order, packing (src, dis[src]) ----------------

__global__ void scatter_k(const int* __restrict__ src, const int* __restrict__ dst,
                          const float* __restrict__ dis,
                          int* __restrict__ cursor, int2* __restrict__ csr, int ne) {
    int e = blockIdx.x * blockDim.x + threadIdx.x;
    if (e >= ne) return;
    int s = src[e];
    int d = dst[e];
    int pos = atomicAdd(&cursor[d], 1);
    csr[pos] = make_int2(s, __float_as_int(dis[s]));
}
// after scatter: cursor[d] == rowoff[d] + indeg(d)  -> row end

// ---------------- GEMM1: hout[n][128] (fp16) = in[n][128] @ W[128][128] ----------------

__global__ __launch_bounds__(256) void gemm1_k(const float* __restrict__ in,
                                               const float* __restrict__ W,
                                               __half* __restrict__ hout, int n_rows) {
    __shared__ float xs[64][132];
    __shared__ float wt[32][128];
    const int t = threadIdx.x;
    const int row0 = blockIdx.x * 64;

    #pragma unroll
    for (int i = 0; i < 8; ++i) {
        int q = t + i * 256;
        int row = q >> 5, c4 = (q & 31) * 4;
        float4 v = make_float4(0.f, 0.f, 0.f, 0.f);
        if (row0 + row < n_rows) v = *(const float4*)(in + (size_t)(row0 + row) * 128 + c4);
        *(float4*)&xs[row][c4] = v;
    }

    const int c4a = (t & 15) * 4;
    const int r4 = (t >> 4) * 4;

    float acc[4][8];
    #pragma unroll
    for (int i = 0; i < 4; ++i)
        #pragma unroll
        for (int j = 0; j < 8; ++j) acc[i][j] = 0.f;

    for (int kt = 0; kt < 4; ++kt) {
        __syncthreads();
        #pragma unroll
        for (int i = 0; i < 4; ++i) {
            int q = t + i * 256;
            int kk = q >> 5, c4 = (q & 31) * 4;
            *(float4*)&wt[kk][c4] = *(const float4*)(W + (size_t)(kt * 32 + kk) * 128 + c4);
        }
        __syncthreads();
        #pragma unroll 4
        for (int k = 0; k < 32; ++k) {
            float xv[4];
            #pragma unroll
            for (int i = 0; i < 4; ++i) xv[i] = xs[r4 + i][kt * 32 + k];
            float4 w0 = *(float4*)&wt[k][c4a];
            float4 w1 = *(float4*)&wt[k][64 + c4a];
            #pragma unroll
            for (int i = 0; i < 4; ++i) {
                acc[i][0] += xv[i] * w0.x; acc[i][1] += xv[i] * w0.y;
                acc[i][2] += xv[i] * w0.z; acc[i][3] += xv[i] * w0.w;
                acc[i][4] += xv[i] * w1.x; acc[i][5] += xv[i] * w1.y;
                acc[i][6] += xv[i] * w1.z; acc[i][7] += xv[i] * w1.w;
            }
        }
    }

    #pragma unroll
    for (int i = 0; i < 4; ++i) {
        int row = row0 + r4 + i;
        if (row < n_rows) {
            __half* p = hout + (size_t)row * 128;
            H4 a, b;
            a.h[0] = __floats2half2_rn(acc[i][0], acc[i][1]);
            a.h[1] = __floats2half2_rn(acc[i][2], acc[i][3]);
            b.h[0] = __floats2half2_rn(acc[i][4], acc[i][5]);
            b.h[1] = __floats2half2_rn(acc[i][6], acc[i][7]);
            *(uint2*)(p + c4a) = a.u;
            *(uint2*)(p + 64 + c4a) = b.u;
        }
    }
}

// ---------------- GEMM2: out[n][32] = relu(in[n][128]) @ W[128][32] ----------------

__global__ __launch_bounds__(256) void gemm2_k(const float* __restrict__ in,
                                               const float* __restrict__ W,
                                               float* __restrict__ out, int n_rows) {
    __shared__ float xs[64][132];
    __shared__ float wt[128][32];
    const int t = threadIdx.x;
    const int row0 = blockIdx.x * 64;

    #pragma unroll
    for (int i = 0; i < 8; ++i) {
        int q = t + i * 256;
        int row = q >> 5, c4 = (q & 31) * 4;
        float4 v = make_float4(0.f, 0.f, 0.f, 0.f);
        if (row0 + row < n_rows) {
            v = *(const float4*)(in + (size_t)(row0 + row) * 128 + c4);
            v.x = fmaxf(v.x, 0.f); v.y = fmaxf(v.y, 0.f);
            v.z = fmaxf(v.z, 0.f); v.w = fmaxf(v.w, 0.f);
        }
        *(float4*)&xs[row][c4] = v;
    }
    #pragma unroll
    for (int i = 0; i < 4; ++i) {
        int q = t + i * 256;
        int kk = q >> 3, c4 = (q & 7) * 4;
        *(float4*)&wt[kk][c4] = *(const float4*)(W + (size_t)kk * 32 + c4);
    }
    __syncthreads();

    const int c4 = (t & 7) * 4;
    const int r2 = (t >> 3) * 2;

    float acc[2][4];
    #pragma unroll
    for (int i = 0; i < 2; ++i)
        #pragma unroll
        for (int j = 0; j < 4; ++j) acc[i][j] = 0.f;

    #pragma unroll 4
    for (int k = 0; k < 128; ++k) {
        float x0 = xs[r2][k], x1 = xs[r2 + 1][k];
        float4 w = *(float4*)&wt[k][c4];
        acc[0][0] += x0 * w.x; acc[0][1] += x0 * w.y; acc[0][2] += x0 * w.z; acc[0][3] += x0 * w.w;
        acc[1][0] += x1 * w.x; acc[1][1] += x1 * w.y; acc[1][2] += x1 * w.z; acc[1][3] += x1 * w.w;
    }

    #pragma unroll
    for (int i = 0; i < 2; ++i) {
        int row = row0 + r2 + i;
        if (row < n_rows)
            *(float4*)(out + (size_t)row * 32 + c4) =
                make_float4(acc[i][0], acc[i][1], acc[i][2], acc[i][3]);
    }
}

// ---------------- GEMM3: out[n][32] = relu(in[n][32]) @ W[32][32] ----------------

__global__ __launch_bounds__(256) void gemm3_k(const float* __restrict__ in,
                                               const float* __restrict__ W,
                                               float* __restrict__ out, int n_rows) {
    __shared__ float xs[64][36];
    __shared__ float wt[32][32];
    const int t = threadIdx.x;
    const int row0 = blockIdx.x * 64;

    #pragma unroll
    for (int i = 0; i < 2; ++i) {
        int q = t + i * 256;
        int row = q >> 3, c4 = (q & 7) * 4;
        float4 v = make_float4(0.f, 0.f, 0.f, 0.f);
        if (row0 + row < n_rows) {
            v = *(const float4*)(in + (size_t)(row0 + row) * 32 + c4);
            v.x = fmaxf(v.x, 0.f); v.y = fmaxf(v.y, 0.f);
            v.z = fmaxf(v.z, 0.f); v.w = fmaxf(v.w, 0.f);
        }
        *(float4*)&xs[row][c4] = v;
    }
    {
        int kk = t >> 3, c4 = (t & 7) * 4;
        *(float4*)&wt[kk][c4] = *(const float4*)(W + (size_t)kk * 32 + c4);
    }
    __syncthreads();

    const int c4 = (t & 7) * 4;
    const int r2 = (t >> 3) * 2;

    float acc[2][4];
    #pragma unroll
    for (int i = 0; i < 2; ++i)
        #pragma unroll
        for (int j = 0; j < 4; ++j) acc[i][j] = 0.f;

    #pragma unroll
    for (int k = 0; k < 32; ++k) {
        float x0 = xs[r2][k], x1 = xs[r2 + 1][k];
        float4 w = *(float4*)&wt[k][c4];
        acc[0][0] += x0 * w.x; acc[0][1] += x0 * w.y; acc[0][2] += x0 * w.z; acc[0][3] += x0 * w.w;
        acc[1][0] += x1 * w.x; acc[1][1] += x1 * w.y; acc[1][2] += x1 * w.z; acc[1][3] += x1 * w.w;
    }

    #pragma unroll
    for (int i = 0; i < 2; ++i) {
        int row = row0 + r2 + i;
        if (row < n_rows)
            *(float4*)(out + (size_t)row * 32 + c4) =
                make_float4(acc[i][0], acc[i][1], acc[i][2], acc[i][3]);
    }
}

// ---------------- pull1 (fp16 h, 128-wide): 16 lanes/node, 8 feat/lane ----------------
// out[d][:] = b + dis[d]*( dis[d]*h[d][:] + sum_e dis[src]*h[src][:] )

__global__ void pull1_k(const __half* __restrict__ h, const int* __restrict__ rowoff,
                        const int* __restrict__ rowend, const int2* __restrict__ csr,
                        const float* __restrict__ dis, const float* __restrict__ b,
                        float* __restrict__ out, int n_nodes) {
    int gt = blockIdx.x * blockDim.x + threadIdx.x;
    int node = gt >> 4;
    int f0 = (gt & 15) * 8;
    if (node >= n_nodes) return;
    int beg = rowoff[node];
    int end = rowend[node];
    float dd = dis[node];

    float acc[8];
    {
        F4H8 v; v.f = *(const float4*)(h + (size_t)node * 128 + f0);
        #pragma unroll
        for (int k = 0; k < 4; ++k) {
            float2 p = __half22float2(v.h[k]);
            acc[2 * k] = dd * p.x; acc[2 * k + 1] = dd * p.y;
        }
    }

    int j = beg;
    for (; j + 2 <= end; j += 2) {
        int2 sw0 = csr[j];
        int2 sw1 = csr[j + 1];
        float w0 = __int_as_float(sw0.y);
        float w1 = __int_as_float(sw1.y);
        F4H8 v0; v0.f = *(const float4*)(h + (size_t)sw0.x * 128 + f0);
        F4H8 v1; v1.f = *(const float4*)(h + (size_t)sw1.x * 128 + f0);
        #pragma unroll
        for (int k = 0; k < 4; ++k) {
            float2 p0 = __half22float2(v0.h[k]);
            float2 p1 = __half22float2(v1.h[k]);
            acc[2 * k]     += w0 * p0.x + w1 * p1.x;
            acc[2 * k + 1] += w0 * p0.y + w1 * p1.y;
        }
    }
    if (j < end) {
        int2 sw = csr[j];
        float w = __int_as_float(sw.y);
        F4H8 v; v.f = *(const float4*)(h + (size_t)sw.x * 128 + f0);
        #pragma unroll
        for (int k = 0; k < 4; ++k) {
            float2 p = __half22float2(v.h[k]);
            acc[2 * k] += w * p.x; acc[2 * k + 1] += w * p.y;
        }
    }

    float* o = out + (size_t)node * 128 + f0;
    float4 b0 = *(const float4*)(b + f0);
    float4 b1 = *(const float4*)(b + f0 + 4);
    *(float4*)o = make_float4(b0.x + dd * acc[0], b0.y + dd * acc[1],
                              b0.z + dd * acc[2], b0.w + dd * acc[3]);
    *(float4*)(o + 4) = make_float4(b1.x + dd * acc[4], b1.y + dd * acc[5],
                                    b1.z + dd * acc[6], b1.w + dd * acc[7]);
}

// ---------------- pull2 (fp32, 32-wide): 8 lanes/node, 4 feat/lane ----------------

__global__ void pull2_k(const float* __restrict__ h, const int* __restrict__ rowoff,
                        const int* __restrict__ rowend, const int2* __restrict__ csr,
                        const float* __restrict__ dis, const float* __restrict__ b,
                        float* __restrict__ out, int n_nodes) {
    int gt = blockIdx.x * blockDim.x + threadIdx.x;
    int node = gt >> 3;
    int f0 = (gt & 7) * 4;
    if (node >= n_nodes) return;
    int beg = rowoff[node];
    int end = rowend[node];
    float dd = dis[node];

    float4 acc = *(const float4*)(h + (size_t)node * 32 + f0);
    acc.x *= dd; acc.y *= dd; acc.z *= dd; acc.w *= dd;

    int j = beg;
    for (; j + 2 <= end; j += 2) {
        int2 sw0 = csr[j];
        int2 sw1 = csr[j + 1];
        float w0 = __int_as_float(sw0.y);
        float w1 = __int_as_float(sw1.y);
        float4 h0 = *(const float4*)(h + (size_t)sw0.x * 32 + f0);
        float4 h1 = *(const float4*)(h + (size_t)sw1.x * 32 + f0);
        acc.x += w0 * h0.x + w1 * h1.x;
        acc.y += w0 * h0.y + w1 * h1.y;
        acc.z += w0 * h0.z + w1 * h1.z;
        acc.w += w0 * h0.w + w1 * h1.w;
    }
    if (j < end) {
        int2 sw = csr[j];
        float w = __int_as_float(sw.y);
        float4 hs = *(const float4*)(h + (size_t)sw.x * 32 + f0);
        acc.x += w * hs.x; acc.y += w * hs.y; acc.z += w * hs.z; acc.w += w * hs.w;
    }

    float4 bb = *(const float4*)(b + f0);
    *(float4*)(out + (size_t)node * 32 + f0) =
        make_float4(bb.x + dd * acc.x, bb.y + dd * acc.y,
                    bb.z + dd * acc.z, bb.w + dd * acc.w);
}

// ---------------- fused pull3 + head (sel nodes only): 8 lanes/sel-entry ----------------

__global__ void pull_head_k(const float* __restrict__ h, const int* __restrict__ rowoff,
                            const int* __restrict__ rowend, const int2* __restrict__ csr,
                            const float* __restrict__ dis, const float* __restrict__ b3,
                            const int* __restrict__ sel, const float* __restrict__ Wl,
                            const float* __restrict__ bl, float* __restrict__ out, int n_sel) {
    int gt = blockIdx.x * blockDim.x + threadIdx.x;
    int t = gt >> 3;
    int f0 = (gt & 7) * 4;
    if (t >= n_sel) return;
    int node = sel[t];
    int beg = rowoff[node];
    int end = rowend[node];
    float dd = dis[node];

    float4 acc = *(const float4*)(h + (size_t)node * 32 + f0);
    acc.x *= dd; acc.y *= dd; acc.z *= dd; acc.w *= dd;

    int j = beg;
    for (; j + 2 <= end; j += 2) {
        int2 sw0 = csr[j];
        int2 sw1 = csr[j + 1];
        float w0 = __int_as_float(sw0.y);
        float w1 = __int_as_float(sw1.y);
        float4 h0 = *(const float4*)(h + (size_t)sw0.x * 32 + f0);
        float4 h1 = *(const float4*)(h + (size_t)sw1.x * 32 + f0);
        acc.x += w0 * h0.x + w1 * h1.x;
        acc.y += w0 * h0.y + w1 * h1.y;
        acc.z += w0 * h0.z + w1 * h1.z;
        acc.w += w0 * h0.w + w1 * h1.w;
    }
    if (j < end) {
        int2 sw = csr[j];
        float w = __int_as_float(sw.y);
        float4 hs = *(const float4*)(h + (size_t)sw.x * 32 + f0);
        acc.x += w * hs.x; acc.y += w * hs.y; acc.z += w * hs.z; acc.w += w * hs.w;
    }

    float4 bb = *(const float4*)(b3 + f0);
    float a0 = bb.x + dd * acc.x;
    float a1 = bb.y + dd * acc.y;
    float a2 = bb.z + dd * acc.z;
    float a3 = bb.w + dd * acc.w;

    float l0 = a0 * Wl[(f0 + 0) * 2] + a1 * Wl[(f0 + 1) * 2]
             + a2 * Wl[(f0 + 2) * 2] + a3 * Wl[(f0 + 3) * 2];
    float l1 = a0 * Wl[(f0 + 0) * 2 + 1] + a1 * Wl[(f0 + 1) * 2 + 1]
             + a2 * Wl[(f0 + 2) * 2 + 1] + a3 * Wl[(f0 + 3) * 2 + 1];
    #pragma unroll
    for (int m = 1; m < 8; m <<= 1) {
        l0 += __shfl_xor(l0, m);
        l1 += __shfl_xor(l1, m);
    }
    if ((gt & 7) == 0) {
        l0 += bl[0]; l1 += bl[1];
        float mx = fmaxf(l0, l1);
        float e0 = expf(l0 - mx), e1 = expf(l1 - mx);
        float s = e0 + e1;
        float ls = logf(s);
        *(float2*)(out + (size_t)t * 2) = make_float2((l0 - mx) - ls, (l1 - mx) - ls);
        *(float2*)(out + 2 * (size_t)n_sel + (size_t)t * 2) = make_float2(e0 / s, e1 / s);
    }
}

// ---------------- launch ----------------

extern "C" void kernel_launch(void* const* d_in, const int* in_sizes, int n_in,
                              void* d_out, int out_size, void* d_ws, size_t ws_size,
                              hipStream_t stream) {
    const float* x  = (const float*)d_in[0];
    const int* edge = (const int*)d_in[1];
    const int* sel  = (const int*)d_in[2];
    const float* W1 = (const float*)d_in[4];
    const float* b1 = (const float*)d_in[5];
    const float* W2 = (const float*)d_in[6];
    const float* b2 = (const float*)d_in[7];
    const float* W3 = (const float*)d_in[8];
    const float* b3 = (const float*)d_in[9];
    const float* Wl = (const float*)d_in[10];
    const float* bl = (const float*)d_in[11];
    float* out = (float*)d_out;

    const int n_nodes = in_sizes[0] / F_IN;
    const int n_edges = in_sizes[1] / 2;
    const int n_sel   = in_sizes[2];
    const int* srcv = edge;
    const int* dstv = edge + n_edges;

    char* ws = (char*)d_ws;
    int*   deg      = (int*)ws;   ws += alignup((size_t)n_nodes * 4);
    float* dis      = (float*)ws; ws += alignup((size_t)n_nodes * 4);
    int*   rowoff   = (int*)ws;   ws += alignup((size_t)n_nodes * 4);
    int*   cursor   = (int*)ws;   ws += alignup((size_t)n_nodes * 4);
    int*   partials = (int*)ws;   ws += alignup(1024);
    int2*  csr      = (int2*)ws;  ws += alignup((size_t)n_edges * 8);
    char*  bufA     = ws;         ws += alignup((size_t)n_nodes * HID * 4);
    float* bufB     = (float*)ws;

    const int B = 256;
    #define GRD(n) (((n) + B - 1) / B)
    const int nblk = GRD(n_nodes);

    // normalization + CSR build (reused by all 3 layers)
    hipMemsetAsync(deg, 0, (size_t)n_nodes * 4, stream);
    deg_count_k<<<GRD(n_edges), B, 0, stream>>>(dstv, deg, n_edges);
    scan_block_k<<<nblk, B, 0, stream>>>(deg, rowoff, partials, n_nodes);
    scan_partials_k<<<1, B, 0, stream>>>(partials, nblk);
    add_offsets_k<<<nblk, B, 0, stream>>>(deg, dis, rowoff, cursor, partials, n_nodes);
    scatter_k<<<GRD(n_edges), B, 0, stream>>>(srcv, dstv, dis, cursor, csr, n_edges);

    const int gemm_blocks = (n_nodes + 63) / 64;

    // layer 1: h1 (fp16) = x @ W1; agg1 = Â h1 + b1 (fp32)
    gemm1_k<<<gemm_blocks, B, 0, stream>>>(x, W1, (__half*)bufA, n_nodes);
    pull1_k<<<GRD(n_nodes * 16), B, 0, stream>>>((const __half*)bufA, rowoff, cursor, csr, dis, b1, bufB, n_nodes);

    // layer 2
    gemm2_k<<<gemm_blocks, B, 0, stream>>>(bufB, W2, (float*)bufA, n_nodes);
    pull2_k<<<GRD(n_nodes * 8), B, 0, stream>>>((const float*)bufA, rowoff, cursor, csr, dis, b2, bufB, n_nodes);

    // layer 3: h3 for all nodes; pull+head only for sel nodes
    gemm3_k<<<gemm_blocks, B, 0, stream>>>(bufB, W3, (float*)bufA, n_nodes);
    pull_head_k<<<GRD(n_sel * 8), B, 0, stream>>>((const float*)bufA, rowoff, cursor, csr, dis, b3,
                                                  sel, Wl, bl, out, n_sel);

    #undef GRD
}